// Round 7
// baseline (8797.885 us; speedup 1.0000x reference)
//
#include <hip/hip_runtime.h>

#define BATCH 512
#define TT 64
#define II 128

// ---------------- workspace layout (floats) ----------------
#define OFF_Wr_e0 0                         // [512][256] rows: [Wih0(x,pad)|Whh0(h0)]
#define OFF_Wr_e1 (OFF_Wr_e0 + 512*256)     // [512][256] rows: [Wih1(h0)|Whh1(h1)]
#define OFF_Wr_d1 (OFF_Wr_e1 + 512*256)     // [512][256] rows: [dWih1(h0)|dWhh1(h1)]
#define OFF_bs0e  (OFF_Wr_d1 + 512*256)
#define OFF_bs1e  (OFF_bs0e + 512)
#define OFF_bs0d  (OFF_bs1e + 512)
#define OFF_bs1d  (OFF_bs0d + 512)
#define OFF_xprojT (OFF_bs1d + 512)          // [B][64j][128e]
#define OFF_hexp   (OFF_xprojT + BATCH*8192) // [B][64t][128k]
#define OFF_hprojT (OFF_hexp + BATCH*8192)   // [B][128kk][64t]

struct Params {
  const float* input;
  const float *eWih0, *eWhh0, *ebih0, *ebhh0, *eWih1, *eWhh1, *ebih1, *ebhh1;
  const float *dWih0, *dWhh0, *dbih0, *dbhh0, *dWih1, *dWhh1, *dbih1, *dbhh1;
  const float *aW1, *ab1, *aW2, *ab2;
  const float *adW1, *adb1, *adW2, *adb2;
  const float *dinW, *dinb, *projW, *projb;
  float* ws;
  float* out;
};

#define L2E 1.4426950408889634f

__device__ __forceinline__ float exp2f_(float x){ return __builtin_amdgcn_exp2f(x); }
__device__ __forceinline__ float rcp_(float x){ return __builtin_amdgcn_rcpf(x); }
__device__ __forceinline__ float fast_tanh(float x){
  float t = exp2f_(x * 2.8853900817779268f);   // e^{2x}
  return 1.f - 2.f * rcp_(t + 1.f);
}
__device__ __forceinline__ float sigm(float x){
  return rcp_(1.f + exp2f_(-x * L2E));
}
__device__ __forceinline__ float wave_max(float v){
  #pragma unroll
  for (int o = 32; o > 0; o >>= 1) v = fmaxf(v, __shfl_xor(v, o, 64));
  return v;
}
__device__ __forceinline__ float wave_sum(float v){
  #pragma unroll
  for (int o = 32; o > 0; o >>= 1) v += __shfl_xor(v, o, 64);
  return v;
}

#define DOT(A,W,X) A += (W).x*(X).x + (W).y*(X).y + (W).z*(X).z + (W).w*(X).w;

// ---------------- prep ----------------
__global__ __launch_bounds__(256) void k_prep(Params p){
  float* ws = p.ws;
  const int gid = blockIdx.x*256 + threadIdx.x;
  const int gsz = gridDim.x*256;
  for (int i = gid; i < 512*256; i += gsz){
    const int j = i >> 8, k = i & 255;
    ws[OFF_Wr_e0 + i] = (k < 128) ? ((k < 127) ? p.eWih0[j*127 + k] : 0.f)
                                  : p.eWhh0[j*128 + (k-128)];
    ws[OFF_Wr_e1 + i] = (k < 128) ? p.eWih1[j*128 + k] : p.eWhh1[j*128 + (k-128)];
    ws[OFF_Wr_d1 + i] = (k < 128) ? p.dWih1[j*128 + k] : p.dWhh1[j*128 + (k-128)];
  }
  for (int i = gid; i < 512; i += gsz){
    ws[OFF_bs0e+i] = p.ebih0[i]+p.ebhh0[i];
    ws[OFF_bs1e+i] = p.ebih1[i]+p.ebhh1[i];
    ws[OFF_bs0d+i] = p.dbih0[i]+p.dbhh0[i];
    ws[OFF_bs1d+i] = p.dbih1[i]+p.dbhh1[i];
  }
}

// ---------------- xprojT[b][j][e] ----------------
__global__ __launch_bounds__(256) void k_xproj(Params p){
  __shared__ float xin[64][128];
  __shared__ float w1x[64][64];
  __shared__ float b1s[64];
  const int b = blockIdx.x, tid = threadIdx.x;
  const float* inb = p.input + (size_t)b*(TT*II);
  for (int i = tid; i < 64*128; i += 256){
    const int k = i >> 7, e = i & 127;
    xin[k][e] = (e < 127) ? inb[k*II + 1 + e] : 0.f;
  }
  for (int i = tid; i < 64*64; i += 256){
    const int j = i >> 6, k = i & 63;
    w1x[j][k] = p.aW1[j*320 + 256 + k];
  }
  if (tid < 64) b1s[tid] = p.ab1[tid];
  __syncthreads();
  float* outb = p.ws + OFF_xprojT + (size_t)b*8192;
  for (int i = tid; i < 64*128; i += 256){
    const int j = i >> 7, e = i & 127;
    float acc = b1s[j];
    #pragma unroll 8
    for (int k = 0; k < 64; ++k) acc += xin[k][e] * w1x[j][k];
    outb[i] = acc;
  }
}

// ---------------- hprojT[b][kk][t] ----------------
__global__ __launch_bounds__(256) void k_hproj(Params p){
  __shared__ float hx[64][129];
  __shared__ float bs[128];
  const int b = blockIdx.x, tid = threadIdx.x;
  const float* hb = p.ws + OFF_hexp + (size_t)b*8192;
  for (int i = tid; i < 64*128; i += 256) hx[i>>7][i&127] = hb[i];
  if (tid < 128) bs[tid] = p.adb1[tid];
  __syncthreads();
  float* outb = p.ws + OFF_hprojT + (size_t)b*8192;
  for (int i = tid; i < 128*64; i += 256){
    const int kk = i >> 6, t2 = i & 63;
    const float* w = p.adW1 + kk*384 + 256;
    float acc = bs[kk];
    #pragma unroll 8
    for (int k = 0; k < 128; ++k) acc += hx[t2][k] * w[k];
    outb[i] = acc;
  }
}

// ---------------- encoder: 512 blocks x 1 batch, 1024 threads ---------------
// Weights register-resident: E1 4 f4, E3 32 f4, E4 32 f4 per thread.
// LDS floats: xp 8192 | Se 512 | c0s 128 | gpA 512 | gpB 512 | scr 1024
//             g01 64 | w2s 64 | pm 2 | psu 2  = 11012 (44,048 B)
#define ENC_LDS_FLOATS (8192+512+128+512+512+1024+64+64+2+2)
__global__ __launch_bounds__(1024) void k_enc(Params p){
  extern __shared__ float sm[];
  float* xp   = sm;            // [j][e] 64x128
  float* Se   = xp + 8192;     // [x(128)|h0|h1|c1]
  float* c0s  = Se + 512;
  float* gpA  = c0s + 128;     // [512]
  float* gpB  = gpA + 512;
  float* scr  = gpB + 512;     // [8][128]
  float* g01  = scr + 1024;    // [64]
  float* w2s  = g01 + 64;
  float* pm   = w2s + 64;
  float* psu  = pm + 2;
  const int tid = threadIdx.x;
  const int b = blockIdx.x;
  float* ws = p.ws;

  { const float4* s = (const float4*)(ws + OFF_xprojT + (size_t)b*8192);
    float4* d = (float4*)xp;
    d[tid] = s[tid];
    d[tid + 1024] = s[tid + 1024]; }
  if (tid < 512) Se[tid] = 0.f;
  if (tid < 128) c0s[tid] = 0.f;
  if (tid < 64) w2s[tid] = p.aW2[tid];
  const float b2 = p.ab2[0];

  // thread maps
  const int kqE = tid & 15, jjE = tid >> 4;   // E1: 64 outputs x 16-way K-split
  const int eA = tid & 127, jq = tid >> 7;    // E2a: 128 e x 8-way j-split
  const int r = tid & 511, kh = tid >> 9;     // gates: 512 rows x 2-way K-split

  // register-resident weights (load-time rotation keeps reg indices STATIC)
  float4 W1[4], W3[32], W4[32];
  #pragma unroll
  for (int i = 0; i < 4; ++i)
    W1[i] = *(const float4*)(p.aW1 + jjE*320 + kqE*16 + ((i + kqE) & 3)*4);
  #pragma unroll
  for (int i = 0; i < 32; ++i)
    W3[i] = *(const float4*)(ws + OFF_Wr_e0 + r*256 + kh*128 + i*4);
  #pragma unroll
  for (int i = 0; i < 32; ++i)
    W4[i] = *(const float4*)(ws + OFF_Wr_e1 + r*256 + kh*128 + i*4);
  const float bias0 = ws[OFF_bs0e + r];
  const float bias1 = ws[OFF_bs1e + r];
  const float* xrow = p.input + (size_t)b*8192;
  __syncthreads();

  for (int t = 0; t < TT; ++t){
    float xreg = 0.f;
    if (tid < 127) xreg = xrow[t*128 + 1 + tid];   // prefetch x_t early
    // --- E1: g01[jj] = [h1|c1] . aW1[jj][0..255], 16-way K-split, shfl
    {
      const float4* X = (const float4*)(Se + 256) + kqE*4;
      float a = 0.f;
      #pragma unroll
      for (int i = 0; i < 4; ++i){ const float4 x = X[(i + kqE) & 3]; DOT(a, W1[i], x) }
      a += __shfl_xor(a,1,64); a += __shfl_xor(a,2,64);
      a += __shfl_xor(a,4,64); a += __shfl_xor(a,8,64);
      if (kqE == 0) g01[jjE] = a;
    }
    __syncthreads();
    // --- E2a: logit partials (8-way j-split, wave-uniform jq)
    {
      float a = 0.f;
      #pragma unroll
      for (int q = 0; q < 8; ++q){
        const int j = jq*8 + q;
        a += w2s[j] * fast_tanh(xp[j*128 + eA] + g01[j]);
      }
      scr[jq*128 + eA] = a;
    }
    __syncthreads();
    // --- E2b: combine + wave softmax partials
    float aL = 0.f;
    if (tid < 128){
      aL = b2;
      #pragma unroll
      for (int q = 0; q < 8; ++q) aL += scr[q*128 + tid];
      if (tid == 127) aL = -3.0e38f;
      const float m = wave_max(aL);
      const float pe = exp2f_((aL - m)*L2E);
      const float s = wave_sum(pe);
      if ((tid & 63) == 0){ pm[tid>>6] = m; psu[tid>>6] = s; }
    }
    __syncthreads();
    // --- E2c: finish softmax, Se.x = a * x_t
    if (tid < 128){
      const float m0 = pm[0], m1 = pm[1];
      const float gm = fmaxf(m0, m1);
      const float tot = psu[0]*exp2f_((m0-gm)*L2E) + psu[1]*exp2f_((m1-gm)*L2E);
      const float aa = exp2f_((aL-gm)*L2E)*rcp_(tot);
      Se[tid] = (tid < 127) ? xreg*aa : 0.f;
    }
    __syncthreads();
    // --- E3: layer0 gates; operand Se[0..255] (x|h0) wave-uniform broadcast
    {
      float a = kh ? 0.f : bias0;
      const float4* X = (const float4*)Se + kh*32;
      #pragma unroll
      for (int kg = 0; kg < 32; ++kg){ const float4 x = X[kg]; DOT(a, W3[kg], x) }
      (kh ? gpB : gpA)[r] = a;
    }
    __syncthreads();
    // --- A0: update h0, c0
    if (tid < 128){
      const float gi = gpA[tid]+gpB[tid], gf = gpA[128+tid]+gpB[128+tid];
      const float gg = gpA[256+tid]+gpB[256+tid], go = gpA[384+tid]+gpB[384+tid];
      const float c = sigm(gf)*c0s[tid] + sigm(gi)*fast_tanh(gg);
      c0s[tid] = c;
      Se[128+tid] = sigm(go)*fast_tanh(c);
    }
    __syncthreads();
    // --- E4: layer1 gates; operand Se[128..383] (h0|h1)
    {
      float a = kh ? 0.f : bias1;
      const float4* X = (const float4*)Se + 32 + kh*32;
      #pragma unroll
      for (int kg = 0; kg < 32; ++kg){ const float4 x = X[kg]; DOT(a, W4[kg], x) }
      (kh ? gpB : gpA)[r] = a;
    }
    __syncthreads();
    // --- A1: update h1, c1, write hexp
    if (tid < 128){
      const float gi = gpA[tid]+gpB[tid], gf = gpA[128+tid]+gpB[128+tid];
      const float gg = gpA[256+tid]+gpB[256+tid], go = gpA[384+tid]+gpB[384+tid];
      const float c = sigm(gf)*Se[384+tid] + sigm(gi)*fast_tanh(gg);
      Se[384+tid] = c;
      const float h = sigm(go)*fast_tanh(c);
      Se[256+tid] = h;
      ws[OFF_hexp + (size_t)b*8192 + t*128 + tid] = h;
    }
    __syncthreads();
  }
}

// ---------------- decoder: 512 blocks x 1 batch, 1024 threads ---------------
// Weights register-resident: D1 8 f4, D3 16 f4, D4 32 f4 per thread.
// LDS floats: hp 8320 | hex 8192 | Sd 384 | c0s 128 | gpA 512 | gpB 512
//             scr 1024 | g01d 128 | abuf 64 | parts 128 | dpart 2 | wd2 128
//             = 19522 (78,088 B)
#define DEC_LDS_FLOATS (8320+8192+384+128+512+512+1024+128+64+128+2+128)
__global__ __launch_bounds__(1024) void k_dec(Params p){
  extern __shared__ float sm[];
  float* hp    = sm;             // [kk][65]
  float* hex   = hp + 8320;      // [t'][h] 64x128
  float* Sd    = hex + 8192;     // [h0|h1|c1]
  float* c0s   = Sd + 384;
  float* gpA   = c0s + 128;
  float* gpB   = gpA + 512;
  float* scr   = gpB + 512;      // [16][64] then [8][128]
  float* g01d  = scr + 1024;     // [128]
  float* abuf  = g01d + 128;     // [64]
  float* parts = abuf + 64;      // [128]
  float* dpart = parts + 128;    // [2]
  float* wd2   = dpart + 2;      // [128]
  const int tid = threadIdx.x;
  const int b = blockIdx.x;
  float* ws = p.ws;

  { const float* s = ws + OFF_hprojT + (size_t)b*8192;
    #pragma unroll
    for (int rep = 0; rep < 8; ++rep){
      const int i = rep*1024 + tid;
      hp[(i>>6)*65 + (i&63)] = s[i];
    }
    const float4* s2 = (const float4*)(ws + OFF_hexp + (size_t)b*8192);
    ((float4*)hex)[tid] = s2[tid];
    ((float4*)hex)[tid + 1024] = s2[tid + 1024];
  }
  if (tid < 384) Sd[tid] = 0.f;
  if (tid < 128) c0s[tid] = 0.f;
  if (tid < 128) wd2[tid] = p.adW2[tid];
  const float bd2 = p.adb2[0];

  // thread maps
  const int kq8 = tid & 7, kkD = tid >> 3;    // D1: 128 outputs x 8-way K-split
  const int tA = tid & 63, kq16 = tid >> 6;   // D2a: 64 t' x 16-way kk-split
  const int hC = tid & 127, tq = tid >> 7;    // D2c: 128 h x 8-way t'-split
  const int r = tid & 511, kh = tid >> 9;     // gates

  float4 WD1[8], WD3[16], WD4[32];
  #pragma unroll
  for (int i = 0; i < 8; ++i)
    WD1[i] = *(const float4*)(p.adW1 + kkD*384 + kq8*32 + ((i + kq8) & 7)*4);
  #pragma unroll
  for (int i = 0; i < 16; ++i)
    WD3[i] = *(const float4*)(p.dWhh0 + r*128 + kh*64 + i*4);
  #pragma unroll
  for (int i = 0; i < 32; ++i)
    WD4[i] = *(const float4*)(ws + OFF_Wr_d1 + r*256 + kh*128 + i*4);
  const float bias0d = ws[OFF_bs0d + r];
  const float bias1d = ws[OFF_bs1d + r];
  const float dW0r = p.dWih0[r];
  const float dinw_h = p.dinW[hC];
  const float dinw128 = p.dinW[128], dinbv = p.dinb[0];
  __syncthreads();

  for (int t = 0; t < TT; ++t){
    const float xd = p.input[(size_t)b*8192 + t*128];   // prefetch, used in D3
    // --- D1: g01d[kk] = [h1|c1] . adW1[kk][0..255], 8-way K-split, shfl
    {
      const float4* X = (const float4*)(Sd + 128) + kq8*8;
      float a = 0.f;
      #pragma unroll
      for (int i = 0; i < 8; ++i){ const float4 x = X[(i + kq8) & 7]; DOT(a, WD1[i], x) }
      a += __shfl_xor(a,1,64); a += __shfl_xor(a,2,64); a += __shfl_xor(a,4,64);
      if (kq8 == 0) g01d[kkD] = a;
    }
    __syncthreads();
    // --- D2a: logit partials over t' (16-way kk-split, wave-uniform kk)
    {
      float a = 0.f;
      #pragma unroll
      for (int q = 0; q < 8; ++q){
        const int kk = kq16*8 + q;
        a += wd2[kk] * fast_tanh(hp[kk*65 + tA] + g01d[kk]);
      }
      scr[kq16*64 + tA] = a;
    }
    __syncthreads();
    // --- D2s: combine + full softmax in wave 0
    if (tid < 64){
      float a = bd2;
      #pragma unroll
      for (int q = 0; q < 16; ++q) a += scr[q*64 + tid];
      const float m = wave_max(a);
      const float pe = exp2f_((a - m)*L2E);
      abuf[tid] = pe * rcp_(wave_sum(pe));
    }
    __syncthreads();
    // --- D2c: parts partial = sum_t' a[t']*hex[t'][h] (8-way t'-split)
    {
      float a = 0.f;
      #pragma unroll
      for (int q = 0; q < 8; ++q){
        const int t2 = tq*8 + q;
        a += abuf[t2] * hex[t2*128 + hC];
      }
      scr[tq*128 + hC] = a;
    }
    __syncthreads();
    // --- D2d: combine parts + din partial
    if (tid < 128){
      float a = 0.f;
      #pragma unroll
      for (int q = 0; q < 8; ++q) a += scr[q*128 + tid];
      parts[tid] = a;
      float v = a * dinw_h;
      v = wave_sum(v);
      if ((tid & 63) == 0) dpart[tid>>6] = v;
    }
    __syncthreads();
    // --- D3: layer0 gates (K=128 h0) + bias + din rank-1
    {
      const float dn = dpart[0] + dpart[1] + xd*dinw128 + dinbv;
      float a = kh ? 0.f : (bias0d + dn*dW0r);
      const float4* X = (const float4*)Sd + kh*16;
      #pragma unroll
      for (int kg = 0; kg < 16; ++kg){ const float4 x = X[kg]; DOT(a, WD3[kg], x) }
      (kh ? gpB : gpA)[r] = a;
    }
    __syncthreads();
    // --- A2: update h0, c0
    if (tid < 128){
      const float gi = gpA[tid]+gpB[tid], gf = gpA[128+tid]+gpB[128+tid];
      const float gg = gpA[256+tid]+gpB[256+tid], go = gpA[384+tid]+gpB[384+tid];
      const float c = sigm(gf)*c0s[tid] + sigm(gi)*fast_tanh(gg);
      c0s[tid] = c;
      Sd[tid] = sigm(go)*fast_tanh(c);
    }
    __syncthreads();
    // --- D4: layer1 gates; operand Sd[0..255] (h0|h1)
    {
      float a = kh ? 0.f : bias1d;
      const float4* X = (const float4*)Sd + kh*32;
      #pragma unroll
      for (int kg = 0; kg < 32; ++kg){ const float4 x = X[kg]; DOT(a, WD4[kg], x) }
      (kh ? gpB : gpA)[r] = a;
    }
    __syncthreads();
    // --- A3: update h1, c1
    if (tid < 128){
      const float gi = gpA[tid]+gpB[tid], gf = gpA[128+tid]+gpB[128+tid];
      const float gg = gpA[256+tid]+gpB[256+tid], go = gpA[384+tid]+gpB[384+tid];
      const float c = sigm(gf)*Sd[256+tid] + sigm(gi)*fast_tanh(gg);
      Sd[256+tid] = c;
      Sd[128+tid] = sigm(go)*fast_tanh(c);
    }
    __syncthreads();
  }
  // --- final projection
  if (tid < 64){
    float v = Sd[128+tid]*p.projW[tid] + Sd[192+tid]*p.projW[64+tid]
            + parts[tid]*p.projW[128+tid] + parts[64+tid]*p.projW[192+tid];
    v = wave_sum(v);
    if (tid == 0) p.out[b] = v + p.projb[0];
  }
}

extern "C" void kernel_launch(void* const* d_in, const int* in_sizes, int n_in,
                              void* d_out, int out_size, void* d_ws, size_t ws_size,
                              hipStream_t stream){
  Params p;
  p.input = (const float*)d_in[0];
  p.eWih0=(const float*)d_in[1];  p.eWhh0=(const float*)d_in[2];
  p.ebih0=(const float*)d_in[3];  p.ebhh0=(const float*)d_in[4];
  p.eWih1=(const float*)d_in[5];  p.eWhh1=(const float*)d_in[6];
  p.ebih1=(const float*)d_in[7];  p.ebhh1=(const float*)d_in[8];
  p.dWih0=(const float*)d_in[9];  p.dWhh0=(const float*)d_in[10];
  p.dbih0=(const float*)d_in[11]; p.dbhh0=(const float*)d_in[12];
  p.dWih1=(const float*)d_in[13]; p.dWhh1=(const float*)d_in[14];
  p.dbih1=(const float*)d_in[15]; p.dbhh1=(const float*)d_in[16];
  p.aW1=(const float*)d_in[17];   p.ab1=(const float*)d_in[18];
  p.aW2=(const float*)d_in[19];   p.ab2=(const float*)d_in[20];
  p.adW1=(const float*)d_in[21];  p.adb1=(const float*)d_in[22];
  p.adW2=(const float*)d_in[23];  p.adb2=(const float*)d_in[24];
  p.dinW=(const float*)d_in[25];  p.dinb=(const float*)d_in[26];
  p.projW=(const float*)d_in[27]; p.projb=(const float*)d_in[28];
  p.ws = (float*)d_ws;
  p.out = (float*)d_out;

  (void)hipFuncSetAttribute(reinterpret_cast<const void*>(k_enc),
      hipFuncAttributeMaxDynamicSharedMemorySize, ENC_LDS_FLOATS*4);
  (void)hipFuncSetAttribute(reinterpret_cast<const void*>(k_dec),
      hipFuncAttributeMaxDynamicSharedMemorySize, DEC_LDS_FLOATS*4);

  hipLaunchKernelGGL(k_prep,  dim3(128), dim3(256), 0, stream, p);
  hipLaunchKernelGGL(k_xproj, dim3(BATCH), dim3(256), 0, stream, p);
  hipLaunchKernelGGL(k_enc,   dim3(BATCH), dim3(1024), ENC_LDS_FLOATS*4, stream, p);
  hipLaunchKernelGGL(k_hproj, dim3(BATCH), dim3(256), 0, stream, p);
  hipLaunchKernelGGL(k_dec,   dim3(BATCH), dim3(1024), DEC_LDS_FLOATS*4, stream, p);
}